// Round 21
// baseline (500.798 us; speedup 1.0000x reference)
//
#include <hip/hip_runtime.h>
#include <stdint.h>

typedef float f32x4 __attribute__((ext_vector_type(4)));
typedef short s16x8 __attribute__((ext_vector_type(8)));
typedef short s16x4 __attribute__((ext_vector_type(4)));

#define MFMA16(a, b, c) __builtin_amdgcn_mfma_f32_16x16x32_bf16(a, b, c, 0, 0, 0)

__device__ __forceinline__ unsigned short f2bf(float f) {
  union { float f; uint32_t u; } v; v.f = f;
  return (unsigned short)((v.u + 0x7FFFu + ((v.u >> 16) & 1u)) >> 16);
}
__device__ __forceinline__ float bf2f(unsigned short s) {
  union { float f; uint32_t u; } v; v.u = ((uint32_t)s) << 16;
  return v.f;
}
// round-half-up f32->bf16 pair pack: 2 adds + 1 v_perm (compiler-visible ops,
// no inline asm -- R12's cvt_pk failure was the opaque asm, not the idea).
// result: low16 = bf16(a), high16 = bf16(b).
__device__ __forceinline__ uint32_t pk2bf(float a, float b) {
  union { float f; uint32_t u; } va, vb;
  va.f = a; vb.f = b;
  return __builtin_amdgcn_perm(vb.u + 0x8000u, va.u + 0x8000u, 0x07060302u);
}
__device__ __forceinline__ s16x8 cvt8(const float* p) {
  f32x4 a = *(const f32x4*)p;
  f32x4 b = *(const f32x4*)(p + 4);
  union { s16x8 s; uint32_t u[4]; } t;
  t.u[0] = pk2bf(a[0], a[1]);
  t.u[1] = pk2bf(a[2], a[3]);
  t.u[2] = pk2bf(b[0], b[1]);
  t.u[3] = pk2bf(b[2], b[3]);
  return t.s;
}
template <int N> __device__ __forceinline__ void vmwait() {
  asm volatile("s_waitcnt vmcnt(%0)" ::"i"(N) : "memory");
}
__device__ __forceinline__ void blockbar() {
  __builtin_amdgcn_s_barrier();
  asm volatile("" ::: "memory");
}
__device__ __forceinline__ void gl_lds16(const void* g, void* l) {
  __builtin_amdgcn_global_load_lds((const __attribute__((address_space(1))) void*)g,
                                   (__attribute__((address_space(3))) void*)l, 16, 0, 0);
}

// ---------------------------------------------------------------------------
// Stage 1: Y = X @ W^T + b. W in LDS (XOR-swizzled), row PAIRS share wfrag
// reads (R19). NEW: all f32->bf16 via pk2bf (add+add+perm per 2 elements,
// 2.7x fewer conversion VALU ops than the 4-op bit-twiddle).
// ---------------------------------------------------------------------------
__global__ __launch_bounds__(256) void proj_kernel(
    const float* __restrict__ Xq, const float* __restrict__ Xk, const float* __restrict__ Xv,
    const float* __restrict__ Wq, const float* __restrict__ bq,
    const float* __restrict__ Wk, const float* __restrict__ bk,
    const float* __restrict__ Wv, const float* __restrict__ bv,
    unsigned short* __restrict__ Qt, unsigned short* __restrict__ Kt,
    unsigned short* __restrict__ Vf) {
  __shared__ unsigned char Wsh[32768];

  const int ty = blockIdx.y;
  const float* X = (ty == 0) ? Xq : (ty == 1) ? Xk : Xv;
  const float* W = (ty == 0) ? Wq : (ty == 1) ? Wk : Wv;
  const float* B = (ty == 0) ? bq : (ty == 1) ? bk : bv;
  unsigned short* out = (ty == 0) ? Qt : (ty == 1) ? Kt : Vf;
  const bool transposed = (ty != 2);

  const int tid = threadIdx.x;
  const int lane = tid & 63;
  const int wave = tid >> 6;
  const int l15 = lane & 15;
  const int g = lane >> 4;

  {
    const int r = tid >> 1;
    const int cb = (tid & 1) * 64;
    const float* wp = W + (size_t)r * 128 + cb;
#pragma unroll
    for (int c8 = 0; c8 < 8; ++c8) {
      s16x8 w = cvt8(wp + 8 * c8);
      const int byte = r * 256 + ((cb * 2 + c8 * 16) ^ ((r & 7) << 4));
      *(s16x8*)(Wsh + byte) = w;
    }
  }
  __syncthreads();

  auto wfrag = [&](int f, int kc) -> s16x8 {
    const int row = 16 * f + l15;
    return *(const s16x8*)(Wsh + row * 256 + ((64 * kc + 16 * g) ^ ((row & 7) << 4)));
  };

  if (transposed) {
    float bias_s[8];
#pragma unroll
    for (int f = 0; f < 8; ++f) bias_s[f] = B[16 * f + l15];

    auto loadX = [&](s16x8 (&xf)[4], int t) {
      const int jb = blockIdx.x * 512 + t * 64 + wave * 16;
      const int jrow = jb + (l15 >> 2) + 4 * (l15 & 3);
      const float* xr = X + (size_t)jrow * 128 + 8 * g;
#pragma unroll
      for (int kc = 0; kc < 4; ++kc) xf[kc] = cvt8(xr + 32 * kc);
    };
    auto storeT = [&](f32x4 (&acc)[8], int t) {
      const int jb = blockIdx.x * 512 + t * 64 + wave * 16;
      const int n = jb >> 9;
      const int c0 = (jb & 511) >> 2;
#pragma unroll
      for (int f = 0; f < 8; ++f) {
        const int h = 128 * g + 16 * f + l15;
        union { s16x4 s; uint32_t u[2]; } pv;
        pv.u[0] = pk2bf(acc[f][0] + bias_s[f], acc[f][1] + bias_s[f]);
        pv.u[1] = pk2bf(acc[f][2] + bias_s[f], acc[f][3] + bias_s[f]);
        *(s16x4*)(out + (size_t)n * 65536 + (size_t)h * 128 + c0) = pv.s;
      }
    };
    auto computePair = [&](s16x8 (&x0)[4], s16x8 (&x1)[4], int t0) {
      f32x4 accA[8], accB[8];
#pragma unroll
      for (int f = 0; f < 8; ++f) {
        accA[f] = (f32x4){0.f, 0.f, 0.f, 0.f};
        accB[f] = (f32x4){0.f, 0.f, 0.f, 0.f};
      }
#pragma unroll
      for (int kc = 0; kc < 4; ++kc)
#pragma unroll
        for (int f = 0; f < 8; ++f) {
          const s16x8 w = wfrag(f, kc);
          accA[f] = MFMA16(x0[kc], w, accA[f]);
          accB[f] = MFMA16(x1[kc], w, accB[f]);
        }
      storeT(accA, t0);
      storeT(accB, t0 + 1);
    };

    s16x8 xA0[4], xA1[4], xB0[4], xB1[4];
    loadX(xA0, 0); loadX(xA1, 1);
#pragma unroll
    for (int tp = 0; tp < 8; tp += 2) {
      if ((tp & 2) == 0) {
        if (tp < 6) { loadX(xB0, tp + 2); loadX(xB1, tp + 3); }
        computePair(xA0, xA1, tp);
      } else {
        if (tp < 6) { loadX(xA0, tp + 2); loadX(xA1, tp + 3); }
        computePair(xB0, xB1, tp);
      }
    }
  } else {
    f32x4 bias_v[8];
#pragma unroll
    for (int f = 0; f < 8; ++f) bias_v[f] = *(const f32x4*)(B + 16 * f + 4 * g);

    auto loadX = [&](s16x8 (&xf)[4], int t) {
      const int jb = blockIdx.x * 512 + t * 64 + wave * 16;
      const int jrow = jb + l15;
      const float* xr = X + (size_t)jrow * 128 + 8 * g;
#pragma unroll
      for (int kc = 0; kc < 4; ++kc) xf[kc] = cvt8(xr + 32 * kc);
    };
    auto storeV = [&](f32x4 (&acc)[8], int t) {
      const int jb = blockIdx.x * 512 + t * 64 + wave * 16;
      const int j = jb + l15;
#pragma unroll
      for (int f = 0; f < 8; ++f) {
        const int cc0 = 16 * f + 4 * g;
        union { s16x4 s; uint32_t u[2]; } pv;
        pv.u[0] = pk2bf(acc[f][0] + bias_v[f][0], acc[f][1] + bias_v[f][1]);
        pv.u[1] = pk2bf(acc[f][2] + bias_v[f][2], acc[f][3] + bias_v[f][3]);
        *(s16x4*)(out + (size_t)j * 128 + cc0) = pv.s;
      }
    };
    auto computePair = [&](s16x8 (&x0)[4], s16x8 (&x1)[4], int t0) {
      f32x4 accA[8], accB[8];
#pragma unroll
      for (int f = 0; f < 8; ++f) {
        accA[f] = (f32x4){0.f, 0.f, 0.f, 0.f};
        accB[f] = (f32x4){0.f, 0.f, 0.f, 0.f};
      }
#pragma unroll
      for (int kc = 0; kc < 4; ++kc)
#pragma unroll
        for (int f = 0; f < 8; ++f) {
          const s16x8 w = wfrag(f, kc);
          accA[f] = MFMA16(w, x0[kc], accA[f]);
          accB[f] = MFMA16(w, x1[kc], accB[f]);
        }
      storeV(accA, t0);
      storeV(accB, t0 + 1);
    };

    s16x8 xA0[4], xA1[4], xB0[4], xB1[4];
    loadX(xA0, 0); loadX(xA1, 1);
#pragma unroll
    for (int tp = 0; tp < 8; tp += 2) {
      if ((tp & 2) == 0) {
        if (tp < 6) { loadX(xB0, tp + 2); loadX(xB1, tp + 3); }
        computePair(xA0, xA1, tp);
      } else {
        if (tp < 6) { loadX(xA0, tp + 2); loadX(xA1, tp + 3); }
        computePair(xB0, xB1, tp);
      }
    }
  }
}

// ---------------------------------------------------------------------------
// Stage 2 (fused): exact R18/R19 (128-row Q-tiles, 8 waves, 1 gl_lds16 per
// wave per window, depth-3 counted vmcnt <2>, named-register P stash,
// end-phase fire-and-forget attn stores). Untouched this round.
// ---------------------------------------------------------------------------
__global__ __launch_bounds__(512, 1) void fattn_kernel(
    const unsigned short* __restrict__ Qt, const unsigned short* __restrict__ Kt,
    const unsigned short* __restrict__ Vf, float* __restrict__ out0,
    float* __restrict__ attn_out) {
  __shared__ unsigned char Stg[32768];  // 4 x 8KB rotating window buffers

  const int tid = threadIdx.x;
  const int lane = tid & 63;
  const int wave = tid >> 6;   // 0..7
  const int l15 = lane & 15;
  const int g = lane >> 4;

  // XCD-aware bijective swizzle (2048 % 8 == 0)
  const int bid = blockIdx.x;
  const int nb = (bid & 7) * 256 + (bid >> 3);
  const int head = nb >> 2;
  const int h0 = (nb & 3) * 128;
  const float scale = 0.08838834764831845f;  // 1/sqrt(128)

  const size_t khead = (size_t)head * 65536;
  const unsigned short* qbase =
      Qt + khead + (size_t)(h0 + 16 * wave + l15) * 128 + 8 * g;
  s16x8 qf0 = *(const s16x8*)(qbase);
  s16x8 qf1 = *(const s16x8*)(qbase + 32);
  s16x8 qf2 = *(const s16x8*)(qbase + 64);
  s16x8 qf3 = *(const s16x8*)(qbase + 96);

  const int sig = 8 * (l15 >> 2) + (l15 & 3);
  const unsigned short* Kh = Kt + khead;
  const unsigned short* Vh = Vf + khead;

  auto stageK = [&](int w) {
    const int i = wave;
    const int cl = i >> 2, kc = i & 3;
    const unsigned short* src =
        Kh + (size_t)sig * 128 + 8 * g + (size_t)w * 4096 + cl * 512 + 32 * kc;
    gl_lds16(src, Stg + (w & 3) * 8192 + i * 1024);
  };
  auto stageV = [&](int w) {
    const int i = wave;
    const int half = i >> 2, fi = i & 3;
    const unsigned short* src =
        Vh + (size_t)l15 * 512 + 8 * g + half * 32768 + w * 32 + (size_t)fi * 8192;
    gl_lds16(src, Stg + (w & 3) * 8192 + i * 1024);
  };

  const int lb = lane * 16;
  s16x8 st0, st1, st2, st3, st4, st5, st6, st7;
  s16x8 st8, st9, st10, st11, st12, st13, st14, st15;
  float rs = 0.f;

#define WINDOW_A(W, ST)                                              \
  do {                                                               \
    const unsigned char* kb8 = Stg + ((W) & 3) * 8192;               \
    s16x8 ka0 = *(const s16x8*)(kb8 + lb);                           \
    s16x8 ka1 = *(const s16x8*)(kb8 + 1024 + lb);                    \
    s16x8 ka2 = *(const s16x8*)(kb8 + 2048 + lb);                    \
    s16x8 ka3 = *(const s16x8*)(kb8 + 3072 + lb);                    \
    s16x8 kb0 = *(const s16x8*)(kb8 + 4096 + lb);                    \
    s16x8 kb1 = *(const s16x8*)(kb8 + 5120 + lb);                    \
    s16x8 kb2 = *(const s16x8*)(kb8 + 6144 + lb);                    \
    s16x8 kb3 = *(const s16x8*)(kb8 + 7168 + lb);                    \
    f32x4 sA = {0.f, 0.f, 0.f, 0.f}, sB = {0.f, 0.f, 0.f, 0.f};      \
    sA = MFMA16(ka0, qf0, sA); sA = MFMA16(ka1, qf1, sA);            \
    sA = MFMA16(ka2, qf2, sA); sA = MFMA16(ka3, qf3, sA);            \
    sB = MFMA16(kb0, qf0, sB); sB = MFMA16(kb1, qf1, sB);            \
    sB = MFMA16(kb2, qf2, sB); sB = MFMA16(kb3, qf3, sB);            \
    s16x8 fr;                                                        \
    float e;                                                         \
    e = __expf(sA[0] * scale); rs += e; fr[0] = (short)f2bf(e);      \
    e = __expf(sA[1] * scale); rs += e; fr[1] = (short)f2bf(e);      \
    e = __expf(sA[2] * scale); rs += e; fr[2] = (short)f2bf(e);      \
    e = __expf(sA[3] * scale); rs += e; fr[3] = (short)f2bf(e);      \
    e = __expf(sB[0] * scale); rs += e; fr[4] = (short)f2bf(e);      \
    e = __expf(sB[1] * scale); rs += e; fr[5] = (short)f2bf(e);      \
    e = __expf(sB[2] * scale); rs += e; fr[6] = (short)f2bf(e);      \
    e = __expf(sB[3] * scale); rs += e; fr[7] = (short)f2bf(e);      \
    ST = fr;                                                         \
  } while (0)

#define STEPA(W, ST)                                                 \
  do { vmwait<2>(); blockbar(); stageK((W) + 3); WINDOW_A(W, ST); } while (0)

  // ---- phase A: 3-deep prefetched K windows (1 load/wave/window) ----
  stageK(0); stageK(1); stageK(2);
  STEPA(0, st0);  STEPA(1, st1);  STEPA(2, st2);  STEPA(3, st3);
  STEPA(4, st4);  STEPA(5, st5);  STEPA(6, st6);  STEPA(7, st7);
  STEPA(8, st8);  STEPA(9, st9);  STEPA(10, st10); STEPA(11, st11);
  STEPA(12, st12);
  vmwait<2>(); blockbar(); WINDOW_A(13, st13);
  vmwait<1>(); blockbar(); WINDOW_A(14, st14);
  vmwait<0>(); blockbar(); WINDOW_A(15, st15);

  // full rowsum for row l15 (combine the 4 g-partials)
  rs += __shfl_xor(rs, 16);
  rs += __shfl_xor(rs, 32);
  const float inv = 1.0f / rs;

  blockbar();  // all waves done with K reads before V staging reuses Stg

  // ---- phase B: 3-deep prefetched V windows, PV from named stash ----
  f32x4 acc2[8];
#pragma unroll
  for (int f = 0; f < 8; ++f) acc2[f] = (f32x4){0.f, 0.f, 0.f, 0.f};

#define WINDOW_B(W, ST)                                                    \
  do {                                                                     \
    const s16x8 pc = ST;                                                   \
    const unsigned char* vb8 = Stg + ((W) & 3) * 8192;                     \
    acc2[0] = MFMA16(pc, *(const s16x8*)(vb8 + lb), acc2[0]);              \
    acc2[1] = MFMA16(pc, *(const s16x8*)(vb8 + 1024 + lb), acc2[1]);       \
    acc2[2] = MFMA16(pc, *(const s16x8*)(vb8 + 2048 + lb), acc2[2]);       \
    acc2[3] = MFMA16(pc, *(const s16x8*)(vb8 + 3072 + lb), acc2[3]);       \
    acc2[4] = MFMA16(pc, *(const s16x8*)(vb8 + 4096 + lb), acc2[4]);       \
    acc2[5] = MFMA16(pc, *(const s16x8*)(vb8 + 5120 + lb), acc2[5]);       \
    acc2[6] = MFMA16(pc, *(const s16x8*)(vb8 + 6144 + lb), acc2[6]);       \
    acc2[7] = MFMA16(pc, *(const s16x8*)(vb8 + 7168 + lb), acc2[7]);       \
  } while (0)

#define STEPB(W, ST)                                                 \
  do { vmwait<2>(); blockbar(); stageV((W) + 3); WINDOW_B(W, ST); } while (0)

  stageV(0); stageV(1); stageV(2);
  STEPB(0, st0);  STEPB(1, st1);  STEPB(2, st2);  STEPB(3, st3);
  STEPB(4, st4);  STEPB(5, st5);  STEPB(6, st6);  STEPB(7, st7);
  STEPB(8, st8);  STEPB(9, st9);  STEPB(10, st10); STEPB(11, st11);
  STEPB(12, st12);
  vmwait<2>(); blockbar(); WINDOW_B(13, st13);
  vmwait<1>(); blockbar(); WINDOW_B(14, st14);
  vmwait<0>(); blockbar(); WINDOW_B(15, st15);

  // ---- phase C: attn from named stash (fire-and-forget stores) ----
  float* ap = attn_out + (size_t)head * 262144 + (size_t)(h0 + 16 * wave + l15) * 512 + 8 * g;

#define OUTW(W, ST)                                                  \
  do {                                                               \
    const s16x8 pc = ST;                                             \
    f32x4 o0, o1;                                                    \
    o0[0] = bf2f((unsigned short)pc[0]) * inv;                       \
    o0[1] = bf2f((unsigned short)pc[1]) * inv;                       \
    o0[2] = bf2f((unsigned short)pc[2]) * inv;                       \
    o0[3] = bf2f((unsigned short)pc[3]) * inv;                       \
    o1[0] = bf2f((unsigned short)pc[4]) * inv;                       \
    o1[1] = bf2f((unsigned short)pc[5]) * inv;                       \
    o1[2] = bf2f((unsigned short)pc[6]) * inv;                       \
    o1[3] = bf2f((unsigned short)pc[7]) * inv;                       \
    *(f32x4*)(ap + (W) * 32) = o0;                                   \
    *(f32x4*)(ap + (W) * 32 + 4) = o1;                               \
  } while (0)

  OUTW(0, st0);  OUTW(1, st1);  OUTW(2, st2);  OUTW(3, st3);
  OUTW(4, st4);  OUTW(5, st5);  OUTW(6, st6);  OUTW(7, st7);
  OUTW(8, st8);  OUTW(9, st9);  OUTW(10, st10); OUTW(11, st11);
  OUTW(12, st12); OUTW(13, st13); OUTW(14, st14); OUTW(15, st15);

  // ---- out0 (normalized, NT: 64B-sector-aligned pattern) ----
  float invm[4];
#pragma unroll
  for (int r = 0; r < 4; ++r) invm[r] = __shfl(inv, 4 * g + r);

  float* op = out0 + khead + (size_t)(h0 + 16 * wave + 4 * g) * 128 + l15;
#pragma unroll
  for (int f = 0; f < 8; ++f)
#pragma unroll
    for (int r = 0; r < 4; ++r)
      __builtin_nontemporal_store(acc2[f][r] * invm[r], op + (size_t)r * 128 + f * 16);
}

extern "C" void kernel_launch(void* const* d_in, const int* in_sizes, int n_in,
                              void* d_out, int out_size, void* d_ws, size_t ws_size,
                              hipStream_t stream) {
  const float* q  = (const float*)d_in[0];
  const float* k  = (const float*)d_in[1];
  const float* v  = (const float*)d_in[2];
  const float* Wq = (const float*)d_in[3];
  const float* bq = (const float*)d_in[4];
  const float* Wk = (const float*)d_in[5];
  const float* bk = (const float*)d_in[6];
  const float* Wv = (const float*)d_in[7];
  const float* bv = (const float*)d_in[8];

  unsigned short* Qt = (unsigned short*)d_ws;       // 64 MiB
  unsigned short* Kt = Qt + 33554432;               // 64 MiB
  unsigned short* Vf = Kt + 33554432;               // 64 MiB
  float* out0 = (float*)d_out;                      // 33,554,432 fp32
  float* attn = out0 + 33554432;                    // 134,217,728 fp32

  dim3 pgrid(512, 3, 1);
  proj_kernel<<<pgrid, 256, 0, stream>>>(q, k, v, Wq, bq, Wk, bk, Wv, bv, Qt, Kt, Vf);
  fattn_kernel<<<2048, 512, 0, stream>>>(Qt, Kt, Vf, out0, attn);
}

// Round 22
// 469.732 us; speedup vs baseline: 1.0661x; 1.0661x over previous
//
#include <hip/hip_runtime.h>
#include <stdint.h>

typedef float f32x4 __attribute__((ext_vector_type(4)));
typedef short s16x8 __attribute__((ext_vector_type(8)));
typedef short s16x4 __attribute__((ext_vector_type(4)));

#define MFMA16(a, b, c) __builtin_amdgcn_mfma_f32_16x16x32_bf16(a, b, c, 0, 0, 0)

__device__ __forceinline__ unsigned short f2bf(float f) {
  union { float f; uint32_t u; } v; v.f = f;
  return (unsigned short)((v.u + 0x7FFFu + ((v.u >> 16) & 1u)) >> 16);
}
__device__ __forceinline__ float bf2f(unsigned short s) {
  union { float f; uint32_t u; } v; v.u = ((uint32_t)s) << 16;
  return v.f;
}
__device__ __forceinline__ s16x8 cvt8(const float* p) {
  f32x4 a = *(const f32x4*)p;
  f32x4 b = *(const f32x4*)(p + 4);
  s16x8 t;
  t[0] = (short)f2bf(a[0]); t[1] = (short)f2bf(a[1]);
  t[2] = (short)f2bf(a[2]); t[3] = (short)f2bf(a[3]);
  t[4] = (short)f2bf(b[0]); t[5] = (short)f2bf(b[1]);
  t[6] = (short)f2bf(b[2]); t[7] = (short)f2bf(b[3]);
  return t;
}
template <int N> __device__ __forceinline__ void vmwait() {
  asm volatile("s_waitcnt vmcnt(%0)" ::"i"(N) : "memory");
}
__device__ __forceinline__ void blockbar() {
  __builtin_amdgcn_s_barrier();
  asm volatile("" ::: "memory");
}
__device__ __forceinline__ void gl_lds16(const void* g, void* l) {
  __builtin_amdgcn_global_load_lds((const __attribute__((address_space(1))) void*)g,
                                   (__attribute__((address_space(3))) void*)l, 16, 0, 0);
}

// ---------------------------------------------------------------------------
// Stage 1: Y = X @ W^T + b. W in LDS (XOR-swizzled), row PAIRS share wfrag
// reads, X double-buffered at pair granularity, bit-twiddle f2bf (the
// verified R19 configuration -- both cvt_pk-asm and perm-pack variants
// regressed ~35-40us; conversion micro-opt is a closed axis).
// ---------------------------------------------------------------------------
__global__ __launch_bounds__(256) void proj_kernel(
    const float* __restrict__ Xq, const float* __restrict__ Xk, const float* __restrict__ Xv,
    const float* __restrict__ Wq, const float* __restrict__ bq,
    const float* __restrict__ Wk, const float* __restrict__ bk,
    const float* __restrict__ Wv, const float* __restrict__ bv,
    unsigned short* __restrict__ Qt, unsigned short* __restrict__ Kt,
    unsigned short* __restrict__ Vf) {
  __shared__ unsigned char Wsh[32768];

  const int ty = blockIdx.y;
  const float* X = (ty == 0) ? Xq : (ty == 1) ? Xk : Xv;
  const float* W = (ty == 0) ? Wq : (ty == 1) ? Wk : Wv;
  const float* B = (ty == 0) ? bq : (ty == 1) ? bk : bv;
  unsigned short* out = (ty == 0) ? Qt : (ty == 1) ? Kt : Vf;
  const bool transposed = (ty != 2);

  const int tid = threadIdx.x;
  const int lane = tid & 63;
  const int wave = tid >> 6;
  const int l15 = lane & 15;
  const int g = lane >> 4;

  {
    const int r = tid >> 1;
    const int cb = (tid & 1) * 64;
    const float* wp = W + (size_t)r * 128 + cb;
#pragma unroll
    for (int c8 = 0; c8 < 8; ++c8) {
      s16x8 w = cvt8(wp + 8 * c8);
      const int byte = r * 256 + ((cb * 2 + c8 * 16) ^ ((r & 7) << 4));
      *(s16x8*)(Wsh + byte) = w;
    }
  }
  __syncthreads();

  auto wfrag = [&](int f, int kc) -> s16x8 {
    const int row = 16 * f + l15;
    return *(const s16x8*)(Wsh + row * 256 + ((64 * kc + 16 * g) ^ ((row & 7) << 4)));
  };

  if (transposed) {
    float bias_s[8];
#pragma unroll
    for (int f = 0; f < 8; ++f) bias_s[f] = B[16 * f + l15];

    auto loadX = [&](s16x8 (&xf)[4], int t) {
      const int jb = blockIdx.x * 512 + t * 64 + wave * 16;
      const int jrow = jb + (l15 >> 2) + 4 * (l15 & 3);
      const float* xr = X + (size_t)jrow * 128 + 8 * g;
#pragma unroll
      for (int kc = 0; kc < 4; ++kc) xf[kc] = cvt8(xr + 32 * kc);
    };
    auto storeT = [&](f32x4 (&acc)[8], int t) {
      const int jb = blockIdx.x * 512 + t * 64 + wave * 16;
      const int n = jb >> 9;
      const int c0 = (jb & 511) >> 2;
#pragma unroll
      for (int f = 0; f < 8; ++f) {
        const int h = 128 * g + 16 * f + l15;
        s16x4 pv;
#pragma unroll
        for (int r = 0; r < 4; ++r) pv[r] = (short)f2bf(acc[f][r] + bias_s[f]);
        *(s16x4*)(out + (size_t)n * 65536 + (size_t)h * 128 + c0) = pv;
      }
    };
    auto computePair = [&](s16x8 (&x0)[4], s16x8 (&x1)[4], int t0) {
      f32x4 accA[8], accB[8];
#pragma unroll
      for (int f = 0; f < 8; ++f) {
        accA[f] = (f32x4){0.f, 0.f, 0.f, 0.f};
        accB[f] = (f32x4){0.f, 0.f, 0.f, 0.f};
      }
#pragma unroll
      for (int kc = 0; kc < 4; ++kc)
#pragma unroll
        for (int f = 0; f < 8; ++f) {
          const s16x8 w = wfrag(f, kc);
          accA[f] = MFMA16(x0[kc], w, accA[f]);
          accB[f] = MFMA16(x1[kc], w, accB[f]);
        }
      storeT(accA, t0);
      storeT(accB, t0 + 1);
    };

    s16x8 xA0[4], xA1[4], xB0[4], xB1[4];
    loadX(xA0, 0); loadX(xA1, 1);
#pragma unroll
    for (int tp = 0; tp < 8; tp += 2) {
      if ((tp & 2) == 0) {
        if (tp < 6) { loadX(xB0, tp + 2); loadX(xB1, tp + 3); }
        computePair(xA0, xA1, tp);
      } else {
        if (tp < 6) { loadX(xA0, tp + 2); loadX(xA1, tp + 3); }
        computePair(xB0, xB1, tp);
      }
    }
  } else {
    f32x4 bias_v[8];
#pragma unroll
    for (int f = 0; f < 8; ++f) bias_v[f] = *(const f32x4*)(B + 16 * f + 4 * g);

    auto loadX = [&](s16x8 (&xf)[4], int t) {
      const int jb = blockIdx.x * 512 + t * 64 + wave * 16;
      const int jrow = jb + l15;
      const float* xr = X + (size_t)jrow * 128 + 8 * g;
#pragma unroll
      for (int kc = 0; kc < 4; ++kc) xf[kc] = cvt8(xr + 32 * kc);
    };
    auto storeV = [&](f32x4 (&acc)[8], int t) {
      const int jb = blockIdx.x * 512 + t * 64 + wave * 16;
      const int j = jb + l15;
#pragma unroll
      for (int f = 0; f < 8; ++f) {
        const int cc0 = 16 * f + 4 * g;
        s16x4 pv;
#pragma unroll
        for (int r = 0; r < 4; ++r) pv[r] = (short)f2bf(acc[f][r] + bias_v[f][r]);
        *(s16x4*)(out + (size_t)j * 128 + cc0) = pv;
      }
    };
    auto computePair = [&](s16x8 (&x0)[4], s16x8 (&x1)[4], int t0) {
      f32x4 accA[8], accB[8];
#pragma unroll
      for (int f = 0; f < 8; ++f) {
        accA[f] = (f32x4){0.f, 0.f, 0.f, 0.f};
        accB[f] = (f32x4){0.f, 0.f, 0.f, 0.f};
      }
#pragma unroll
      for (int kc = 0; kc < 4; ++kc)
#pragma unroll
        for (int f = 0; f < 8; ++f) {
          const s16x8 w = wfrag(f, kc);
          accA[f] = MFMA16(w, x0[kc], accA[f]);
          accB[f] = MFMA16(w, x1[kc], accB[f]);
        }
      storeV(accA, t0);
      storeV(accB, t0 + 1);
    };

    s16x8 xA0[4], xA1[4], xB0[4], xB1[4];
    loadX(xA0, 0); loadX(xA1, 1);
#pragma unroll
    for (int tp = 0; tp < 8; tp += 2) {
      if ((tp & 2) == 0) {
        if (tp < 6) { loadX(xB0, tp + 2); loadX(xB1, tp + 3); }
        computePair(xA0, xA1, tp);
      } else {
        if (tp < 6) { loadX(xA0, tp + 2); loadX(xA1, tp + 3); }
        computePair(xB0, xB1, tp);
      }
    }
  }
}

// ---------------------------------------------------------------------------
// Stage 2 (fused): exact R18/R19 (128-row Q-tiles, 8 waves, 1 gl_lds16 per
// wave per window, depth-3 counted vmcnt <2>, named-register P stash,
// end-phase fire-and-forget attn stores).
// ---------------------------------------------------------------------------
__global__ __launch_bounds__(512, 1) void fattn_kernel(
    const unsigned short* __restrict__ Qt, const unsigned short* __restrict__ Kt,
    const unsigned short* __restrict__ Vf, float* __restrict__ out0,
    float* __restrict__ attn_out) {
  __shared__ unsigned char Stg[32768];  // 4 x 8KB rotating window buffers

  const int tid = threadIdx.x;
  const int lane = tid & 63;
  const int wave = tid >> 6;   // 0..7
  const int l15 = lane & 15;
  const int g = lane >> 4;

  // XCD-aware bijective swizzle (2048 % 8 == 0)
  const int bid = blockIdx.x;
  const int nb = (bid & 7) * 256 + (bid >> 3);
  const int head = nb >> 2;
  const int h0 = (nb & 3) * 128;
  const float scale = 0.08838834764831845f;  // 1/sqrt(128)

  const size_t khead = (size_t)head * 65536;
  const unsigned short* qbase =
      Qt + khead + (size_t)(h0 + 16 * wave + l15) * 128 + 8 * g;
  s16x8 qf0 = *(const s16x8*)(qbase);
  s16x8 qf1 = *(const s16x8*)(qbase + 32);
  s16x8 qf2 = *(const s16x8*)(qbase + 64);
  s16x8 qf3 = *(const s16x8*)(qbase + 96);

  const int sig = 8 * (l15 >> 2) + (l15 & 3);
  const unsigned short* Kh = Kt + khead;
  const unsigned short* Vh = Vf + khead;

  auto stageK = [&](int w) {
    const int i = wave;
    const int cl = i >> 2, kc = i & 3;
    const unsigned short* src =
        Kh + (size_t)sig * 128 + 8 * g + (size_t)w * 4096 + cl * 512 + 32 * kc;
    gl_lds16(src, Stg + (w & 3) * 8192 + i * 1024);
  };
  auto stageV = [&](int w) {
    const int i = wave;
    const int half = i >> 2, fi = i & 3;
    const unsigned short* src =
        Vh + (size_t)l15 * 512 + 8 * g + half * 32768 + w * 32 + (size_t)fi * 8192;
    gl_lds16(src, Stg + (w & 3) * 8192 + i * 1024);
  };

  const int lb = lane * 16;
  s16x8 st0, st1, st2, st3, st4, st5, st6, st7;
  s16x8 st8, st9, st10, st11, st12, st13, st14, st15;
  float rs = 0.f;

#define WINDOW_A(W, ST)                                              \
  do {                                                               \
    const unsigned char* kb8 = Stg + ((W) & 3) * 8192;               \
    s16x8 ka0 = *(const s16x8*)(kb8 + lb);                           \
    s16x8 ka1 = *(const s16x8*)(kb8 + 1024 + lb);                    \
    s16x8 ka2 = *(const s16x8*)(kb8 + 2048 + lb);                    \
    s16x8 ka3 = *(const s16x8*)(kb8 + 3072 + lb);                    \
    s16x8 kb0 = *(const s16x8*)(kb8 + 4096 + lb);                    \
    s16x8 kb1 = *(const s16x8*)(kb8 + 5120 + lb);                    \
    s16x8 kb2 = *(const s16x8*)(kb8 + 6144 + lb);                    \
    s16x8 kb3 = *(const s16x8*)(kb8 + 7168 + lb);                    \
    f32x4 sA = {0.f, 0.f, 0.f, 0.f}, sB = {0.f, 0.f, 0.f, 0.f};      \
    sA = MFMA16(ka0, qf0, sA); sA = MFMA16(ka1, qf1, sA);            \
    sA = MFMA16(ka2, qf2, sA); sA = MFMA16(ka3, qf3, sA);            \
    sB = MFMA16(kb0, qf0, sB); sB = MFMA16(kb1, qf1, sB);            \
    sB = MFMA16(kb2, qf2, sB); sB = MFMA16(kb3, qf3, sB);            \
    s16x8 fr;                                                        \
    float e;                                                         \
    e = __expf(sA[0] * scale); rs += e; fr[0] = (short)f2bf(e);      \
    e = __expf(sA[1] * scale); rs += e; fr[1] = (short)f2bf(e);      \
    e = __expf(sA[2] * scale); rs += e; fr[2] = (short)f2bf(e);      \
    e = __expf(sA[3] * scale); rs += e; fr[3] = (short)f2bf(e);      \
    e = __expf(sB[0] * scale); rs += e; fr[4] = (short)f2bf(e);      \
    e = __expf(sB[1] * scale); rs += e; fr[5] = (short)f2bf(e);      \
    e = __expf(sB[2] * scale); rs += e; fr[6] = (short)f2bf(e);      \
    e = __expf(sB[3] * scale); rs += e; fr[7] = (short)f2bf(e);      \
    ST = fr;                                                         \
  } while (0)

#define STEPA(W, ST)                                                 \
  do { vmwait<2>(); blockbar(); stageK((W) + 3); WINDOW_A(W, ST); } while (0)

  // ---- phase A: 3-deep prefetched K windows (1 load/wave/window) ----
  stageK(0); stageK(1); stageK(2);
  STEPA(0, st0);  STEPA(1, st1);  STEPA(2, st2);  STEPA(3, st3);
  STEPA(4, st4);  STEPA(5, st5);  STEPA(6, st6);  STEPA(7, st7);
  STEPA(8, st8);  STEPA(9, st9);  STEPA(10, st10); STEPA(11, st11);
  STEPA(12, st12);
  vmwait<2>(); blockbar(); WINDOW_A(13, st13);
  vmwait<1>(); blockbar(); WINDOW_A(14, st14);
  vmwait<0>(); blockbar(); WINDOW_A(15, st15);

  // full rowsum for row l15 (combine the 4 g-partials)
  rs += __shfl_xor(rs, 16);
  rs += __shfl_xor(rs, 32);
  const float inv = 1.0f / rs;

  blockbar();  // all waves done with K reads before V staging reuses Stg

  // ---- phase B: 3-deep prefetched V windows, PV from named stash ----
  f32x4 acc2[8];
#pragma unroll
  for (int f = 0; f < 8; ++f) acc2[f] = (f32x4){0.f, 0.f, 0.f, 0.f};

#define WINDOW_B(W, ST)                                                    \
  do {                                                                     \
    const s16x8 pc = ST;                                                   \
    const unsigned char* vb8 = Stg + ((W) & 3) * 8192;                     \
    acc2[0] = MFMA16(pc, *(const s16x8*)(vb8 + lb), acc2[0]);              \
    acc2[1] = MFMA16(pc, *(const s16x8*)(vb8 + 1024 + lb), acc2[1]);       \
    acc2[2] = MFMA16(pc, *(const s16x8*)(vb8 + 2048 + lb), acc2[2]);       \
    acc2[3] = MFMA16(pc, *(const s16x8*)(vb8 + 3072 + lb), acc2[3]);       \
    acc2[4] = MFMA16(pc, *(const s16x8*)(vb8 + 4096 + lb), acc2[4]);       \
    acc2[5] = MFMA16(pc, *(const s16x8*)(vb8 + 5120 + lb), acc2[5]);       \
    acc2[6] = MFMA16(pc, *(const s16x8*)(vb8 + 6144 + lb), acc2[6]);       \
    acc2[7] = MFMA16(pc, *(const s16x8*)(vb8 + 7168 + lb), acc2[7]);       \
  } while (0)

#define STEPB(W, ST)                                                 \
  do { vmwait<2>(); blockbar(); stageV((W) + 3); WINDOW_B(W, ST); } while (0)

  stageV(0); stageV(1); stageV(2);
  STEPB(0, st0);  STEPB(1, st1);  STEPB(2, st2);  STEPB(3, st3);
  STEPB(4, st4);  STEPB(5, st5);  STEPB(6, st6);  STEPB(7, st7);
  STEPB(8, st8);  STEPB(9, st9);  STEPB(10, st10); STEPB(11, st11);
  STEPB(12, st12);
  vmwait<2>(); blockbar(); WINDOW_B(13, st13);
  vmwait<1>(); blockbar(); WINDOW_B(14, st14);
  vmwait<0>(); blockbar(); WINDOW_B(15, st15);

  // ---- phase C: attn from named stash (fire-and-forget stores) ----
  float* ap = attn_out + (size_t)head * 262144 + (size_t)(h0 + 16 * wave + l15) * 512 + 8 * g;

#define OUTW(W, ST)                                                  \
  do {                                                               \
    const s16x8 pc = ST;                                             \
    f32x4 o0, o1;                                                    \
    o0[0] = bf2f((unsigned short)pc[0]) * inv;                       \
    o0[1] = bf2f((unsigned short)pc[1]) * inv;                       \
    o0[2] = bf2f((unsigned short)pc[2]) * inv;                       \
    o0[3] = bf2f((unsigned short)pc[3]) * inv;                       \
    o1[0] = bf2f((unsigned short)pc[4]) * inv;                       \
    o1[1] = bf2f((unsigned short)pc[5]) * inv;                       \
    o1[2] = bf2f((unsigned short)pc[6]) * inv;                       \
    o1[3] = bf2f((unsigned short)pc[7]) * inv;                       \
    *(f32x4*)(ap + (W) * 32) = o0;                                   \
    *(f32x4*)(ap + (W) * 32 + 4) = o1;                               \
  } while (0)

  OUTW(0, st0);  OUTW(1, st1);  OUTW(2, st2);  OUTW(3, st3);
  OUTW(4, st4);  OUTW(5, st5);  OUTW(6, st6);  OUTW(7, st7);
  OUTW(8, st8);  OUTW(9, st9);  OUTW(10, st10); OUTW(11, st11);
  OUTW(12, st12); OUTW(13, st13); OUTW(14, st14); OUTW(15, st15);

  // ---- out0 (normalized, NT: 64B-sector-aligned pattern) ----
  float invm[4];
#pragma unroll
  for (int r = 0; r < 4; ++r) invm[r] = __shfl(inv, 4 * g + r);

  float* op = out0 + khead + (size_t)(h0 + 16 * wave + 4 * g) * 128 + l15;
#pragma unroll
  for (int f = 0; f < 8; ++f)
#pragma unroll
    for (int r = 0; r < 4; ++r)
      __builtin_nontemporal_store(acc2[f][r] * invm[r], op + (size_t)r * 128 + f * 16);
}

extern "C" void kernel_launch(void* const* d_in, const int* in_sizes, int n_in,
                              void* d_out, int out_size, void* d_ws, size_t ws_size,
                              hipStream_t stream) {
  const float* q  = (const float*)d_in[0];
  const float* k  = (const float*)d_in[1];
  const float* v  = (const float*)d_in[2];
  const float* Wq = (const float*)d_in[3];
  const float* bq = (const float*)d_in[4];
  const float* Wk = (const float*)d_in[5];
  const float* bk = (const float*)d_in[6];
  const float* Wv = (const float*)d_in[7];
  const float* bv = (const float*)d_in[8];

  unsigned short* Qt = (unsigned short*)d_ws;       // 64 MiB
  unsigned short* Kt = Qt + 33554432;               // 64 MiB
  unsigned short* Vf = Kt + 33554432;               // 64 MiB
  float* out0 = (float*)d_out;                      // 33,554,432 fp32
  float* attn = out0 + 33554432;                    // 134,217,728 fp32

  dim3 pgrid(512, 3, 1);
  proj_kernel<<<pgrid, 256, 0, stream>>>(q, k, v, Wq, bq, Wk, bk, Wv, bv, Qt, Kt, Vf);
  fattn_kernel<<<2048, 512, 0, stream>>>(Qt, Kt, Vf, out0, attn);
}

// Round 24
// 461.342 us; speedup vs baseline: 1.0855x; 1.0182x over previous
//
#include <hip/hip_runtime.h>
#include <stdint.h>

typedef float f32x4 __attribute__((ext_vector_type(4)));
typedef short s16x8 __attribute__((ext_vector_type(8)));
typedef short s16x4 __attribute__((ext_vector_type(4)));

#define MFMA16(a, b, c) __builtin_amdgcn_mfma_f32_16x16x32_bf16(a, b, c, 0, 0, 0)

__device__ __forceinline__ unsigned short f2bf(float f) {
  union { float f; uint32_t u; } v; v.f = f;
  return (unsigned short)((v.u + 0x7FFFu + ((v.u >> 16) & 1u)) >> 16);
}
__device__ __forceinline__ float bf2f(unsigned short s) {
  union { float f; uint32_t u; } v; v.u = ((uint32_t)s) << 16;
  return v.f;
}
__device__ __forceinline__ s16x8 cvt8(const float* p) {
  f32x4 a = *(const f32x4*)p;
  f32x4 b = *(const f32x4*)(p + 4);
  s16x8 t;
  t[0] = (short)f2bf(a[0]); t[1] = (short)f2bf(a[1]);
  t[2] = (short)f2bf(a[2]); t[3] = (short)f2bf(a[3]);
  t[4] = (short)f2bf(b[0]); t[5] = (short)f2bf(b[1]);
  t[6] = (short)f2bf(b[2]); t[7] = (short)f2bf(b[3]);
  return t;
}
template <int N> __device__ __forceinline__ void vmwait() {
  asm volatile("s_waitcnt vmcnt(%0)" ::"i"(N) : "memory");
}
__device__ __forceinline__ void blockbar() {
  __builtin_amdgcn_s_barrier();
  asm volatile("" ::: "memory");
}
__device__ __forceinline__ void gl_lds16(const void* g, void* l) {
  __builtin_amdgcn_global_load_lds((const __attribute__((address_space(1))) void*)g,
                                   (__attribute__((address_space(3))) void*)l, 16, 0, 0);
}

// ---------------------------------------------------------------------------
// Stage 1: Y = X @ W^T + b for K and V ONLY (Q fused into fattn).
// W in LDS (XOR-swizzled), row PAIRS share wfrag reads, X double-buffered.
// ---------------------------------------------------------------------------
__global__ __launch_bounds__(256) void proj_kernel(
    const float* __restrict__ Xk, const float* __restrict__ Xv,
    const float* __restrict__ Wk, const float* __restrict__ bk,
    const float* __restrict__ Wv, const float* __restrict__ bv,
    unsigned short* __restrict__ Kt, unsigned short* __restrict__ Vf) {
  __shared__ unsigned char Wsh[32768];

  const int ty = blockIdx.y;
  const float* X = (ty == 0) ? Xk : Xv;
  const float* W = (ty == 0) ? Wk : Wv;
  const float* B = (ty == 0) ? bk : bv;
  unsigned short* out = (ty == 0) ? Kt : Vf;
  const bool transposed = (ty == 0);

  const int tid = threadIdx.x;
  const int lane = tid & 63;
  const int wave = tid >> 6;
  const int l15 = lane & 15;
  const int g = lane >> 4;

  {
    const int r = tid >> 1;
    const int cb = (tid & 1) * 64;
    const float* wp = W + (size_t)r * 128 + cb;
#pragma unroll
    for (int c8 = 0; c8 < 8; ++c8) {
      s16x8 w = cvt8(wp + 8 * c8);
      const int byte = r * 256 + ((cb * 2 + c8 * 16) ^ ((r & 7) << 4));
      *(s16x8*)(Wsh + byte) = w;
    }
  }
  __syncthreads();

  auto wfrag = [&](int f, int kc) -> s16x8 {
    const int row = 16 * f + l15;
    return *(const s16x8*)(Wsh + row * 256 + ((64 * kc + 16 * g) ^ ((row & 7) << 4)));
  };

  if (transposed) {
    float bias_s[8];
#pragma unroll
    for (int f = 0; f < 8; ++f) bias_s[f] = B[16 * f + l15];

    auto loadX = [&](s16x8 (&xf)[4], int t) {
      const int jb = blockIdx.x * 512 + t * 64 + wave * 16;
      const int jrow = jb + (l15 >> 2) + 4 * (l15 & 3);
      const float* xr = X + (size_t)jrow * 128 + 8 * g;
#pragma unroll
      for (int kc = 0; kc < 4; ++kc) xf[kc] = cvt8(xr + 32 * kc);
    };
    auto storeT = [&](f32x4 (&acc)[8], int t) {
      const int jb = blockIdx.x * 512 + t * 64 + wave * 16;
      const int n = jb >> 9;
      const int c0 = (jb & 511) >> 2;
#pragma unroll
      for (int f = 0; f < 8; ++f) {
        const int h = 128 * g + 16 * f + l15;
        s16x4 pv;
#pragma unroll
        for (int r = 0; r < 4; ++r) pv[r] = (short)f2bf(acc[f][r] + bias_s[f]);
        *(s16x4*)(out + (size_t)n * 65536 + (size_t)h * 128 + c0) = pv;
      }
    };
    auto computePair = [&](s16x8 (&x0)[4], s16x8 (&x1)[4], int t0) {
      f32x4 accA[8], accB[8];
#pragma unroll
      for (int f = 0; f < 8; ++f) {
        accA[f] = (f32x4){0.f, 0.f, 0.f, 0.f};
        accB[f] = (f32x4){0.f, 0.f, 0.f, 0.f};
      }
#pragma unroll
      for (int kc = 0; kc < 4; ++kc)
#pragma unroll
        for (int f = 0; f < 8; ++f) {
          const s16x8 w = wfrag(f, kc);
          accA[f] = MFMA16(x0[kc], w, accA[f]);
          accB[f] = MFMA16(x1[kc], w, accB[f]);
        }
      storeT(accA, t0);
      storeT(accB, t0 + 1);
    };

    s16x8 xA0[4], xA1[4], xB0[4], xB1[4];
    loadX(xA0, 0); loadX(xA1, 1);
#pragma unroll
    for (int tp = 0; tp < 8; tp += 2) {
      if ((tp & 2) == 0) {
        if (tp < 6) { loadX(xB0, tp + 2); loadX(xB1, tp + 3); }
        computePair(xA0, xA1, tp);
      } else {
        if (tp < 6) { loadX(xA0, tp + 2); loadX(xA1, tp + 3); }
        computePair(xB0, xB1, tp);
      }
    }
  } else {
    f32x4 bias_v[8];
#pragma unroll
    for (int f = 0; f < 8; ++f) bias_v[f] = *(const f32x4*)(B + 16 * f + 4 * g);

    auto loadX = [&](s16x8 (&xf)[4], int t) {
      const int jb = blockIdx.x * 512 + t * 64 + wave * 16;
      const int jrow = jb + l15;
      const float* xr = X + (size_t)jrow * 128 + 8 * g;
#pragma unroll
      for (int kc = 0; kc < 4; ++kc) xf[kc] = cvt8(xr + 32 * kc);
    };
    auto storeV = [&](f32x4 (&acc)[8], int t) {
      const int jb = blockIdx.x * 512 + t * 64 + wave * 16;
      const int j = jb + l15;
#pragma unroll
      for (int f = 0; f < 8; ++f) {
        const int cc0 = 16 * f + 4 * g;
        s16x4 pv;
#pragma unroll
        for (int r = 0; r < 4; ++r) pv[r] = (short)f2bf(acc[f][r] + bias_v[f][r]);
        *(s16x4*)(out + (size_t)j * 128 + cc0) = pv;
      }
    };
    auto computePair = [&](s16x8 (&x0)[4], s16x8 (&x1)[4], int t0) {
      f32x4 accA[8], accB[8];
#pragma unroll
      for (int f = 0; f < 8; ++f) {
        accA[f] = (f32x4){0.f, 0.f, 0.f, 0.f};
        accB[f] = (f32x4){0.f, 0.f, 0.f, 0.f};
      }
#pragma unroll
      for (int kc = 0; kc < 4; ++kc)
#pragma unroll
        for (int f = 0; f < 8; ++f) {
          const s16x8 w = wfrag(f, kc);
          accA[f] = MFMA16(w, x0[kc], accA[f]);
          accB[f] = MFMA16(w, x1[kc], accB[f]);
        }
      storeV(accA, t0);
      storeV(accB, t0 + 1);
    };

    s16x8 xA0[4], xA1[4], xB0[4], xB1[4];
    loadX(xA0, 0); loadX(xA1, 1);
#pragma unroll
    for (int tp = 0; tp < 8; tp += 2) {
      if ((tp & 2) == 0) {
        if (tp < 6) { loadX(xB0, tp + 2); loadX(xB1, tp + 3); }
        computePair(xA0, xA1, tp);
      } else {
        if (tp < 6) { loadX(xA0, tp + 2); loadX(xA1, tp + 3); }
        computePair(xB0, xB1, tp);
      }
    }
  }
}

// ---------------------------------------------------------------------------
// Stage 2 (fused + inline Q-projection): per (head, 128-row Q-tile), 8 waves.
// The block's Q-tile Q[h0+cc][c] equals Y[j = 512*head + 4c + q4][cc]
// (q4 = h0>>7), i.e. X rows with stride 4. IDENTITY row feed (A row m ->
// j = 512*head + 64*wave + 4*m + q4) makes C row m'=4g+r land at
// c = 16*wave + 4g + r -- contiguous in r, so the s16x4 pack stores
// directly into XOR-swizzled Qsh[128][128]. (R22 wrongly applied the
// sigma permutation on top -> g/r swap in c -> absmax 4.2e-3.)
// ---------------------------------------------------------------------------
__global__ __launch_bounds__(512, 1) void fattn_kernel(
    const float* __restrict__ Xq, const float* __restrict__ Wq,
    const float* __restrict__ bq,
    const unsigned short* __restrict__ Kt, const unsigned short* __restrict__ Vf,
    float* __restrict__ out0, float* __restrict__ attn_out) {
  __shared__ unsigned char Stg[32768];  // Wq staging first, then 4x8KB rotating buffers
  __shared__ unsigned char Qsh[32768];  // Q[128][128] bf16, byte ^= (h&7)<<4

  const int tid = threadIdx.x;
  const int lane = tid & 63;
  const int wave = tid >> 6;   // 0..7
  const int l15 = lane & 15;
  const int g = lane >> 4;

  // XCD-aware bijective swizzle (2048 % 8 == 0)
  const int bid = blockIdx.x;
  const int nb = (bid & 7) * 256 + (bid >> 3);
  const int head = nb >> 2;
  const int h0 = (nb & 3) * 128;
  const float scale = 0.08838834764831845f;  // 1/sqrt(128)

  // ---- prologue 1: Wq -> Stg (as Wsh), 512 threads ----
  {
    const int r = tid >> 2;            // 0..127
    const int cb2 = (tid & 3) * 32;    // elements
    const float* wp = Wq + (size_t)r * 128 + cb2;
#pragma unroll
    for (int c8 = 0; c8 < 4; ++c8) {
      s16x8 w = cvt8(wp + 8 * c8);
      const int byte = r * 256 + ((cb2 * 2 + c8 * 16) ^ ((r & 7) << 4));
      *(s16x8*)(Stg + byte) = w;
    }
  }
  __syncthreads();

  // ---- prologue 2: Q-tile projection into Qsh ----
  {
    auto wfrag = [&](int f, int kc) -> s16x8 {
      const int row = 16 * f + l15;
      return *(const s16x8*)(Stg + row * 256 + ((64 * kc + 16 * g) ^ ((row & 7) << 4)));
    };
    const int q4 = nb & 3;             // h0 >> 7
    const int jrow = 512 * head + 64 * wave + 4 * l15 + q4;   // IDENTITY feed
    const float* xr = Xq + (size_t)jrow * 128 + 8 * g;
    s16x8 xf[4];
#pragma unroll
    for (int kc = 0; kc < 4; ++kc) xf[kc] = cvt8(xr + 32 * kc);

    float bias_s[8];
#pragma unroll
    for (int f = 0; f < 8; ++f) bias_s[f] = bq[16 * f + l15];

    f32x4 acc[8];
#pragma unroll
    for (int f = 0; f < 8; ++f) acc[f] = (f32x4){0.f, 0.f, 0.f, 0.f};
#pragma unroll
    for (int kc = 0; kc < 4; ++kc)
#pragma unroll
      for (int f = 0; f < 8; ++f) acc[f] = MFMA16(xf[kc], wfrag(f, kc), acc[f]);

    // acc[f][r] = Q[h_local = 16f + l15][c = 16*wave + 4g + r]
    const int c0 = 16 * wave + 4 * g;
#pragma unroll
    for (int f = 0; f < 8; ++f) {
      const int h = 16 * f + l15;
      s16x4 pv;
#pragma unroll
      for (int r = 0; r < 4; ++r) pv[r] = (short)f2bf(acc[f][r] + bias_s[f]);
      *(s16x4*)(Qsh + h * 256 + ((c0 * 2) ^ ((h & 7) << 4))) = pv;
    }
  }
  __syncthreads();  // Qsh complete; Stg free for staging reuse

  // ---- qf from Qsh (local row hq = 16*wave + l15) ----
  const int hq = 16 * wave + l15;
  const int qsw = (hq & 7) << 4;
  s16x8 qf0 = *(const s16x8*)(Qsh + hq * 256 + ((0 + 16 * g) ^ qsw));
  s16x8 qf1 = *(const s16x8*)(Qsh + hq * 256 + ((64 + 16 * g) ^ qsw));
  s16x8 qf2 = *(const s16x8*)(Qsh + hq * 256 + ((128 + 16 * g) ^ qsw));
  s16x8 qf3 = *(const s16x8*)(Qsh + hq * 256 + ((192 + 16 * g) ^ qsw));

  const size_t khead = (size_t)head * 65536;
  const int sig = 8 * (l15 >> 2) + (l15 & 3);
  const unsigned short* Kh = Kt + khead;
  const unsigned short* Vh = Vf + khead;

  auto stageK = [&](int w) {
    const int i = wave;
    const int cl = i >> 2, kc = i & 3;
    const unsigned short* src =
        Kh + (size_t)sig * 128 + 8 * g + (size_t)w * 4096 + cl * 512 + 32 * kc;
    gl_lds16(src, Stg + (w & 3) * 8192 + i * 1024);
  };
  auto stageV = [&](int w) {
    const int i = wave;
    const int half = i >> 2, fi = i & 3;
    const unsigned short* src =
        Vh + (size_t)l15 * 512 + 8 * g + half * 32768 + w * 32 + (size_t)fi * 8192;
    gl_lds16(src, Stg + (w & 3) * 8192 + i * 1024);
  };

  const int lb = lane * 16;
  s16x8 st0, st1, st2, st3, st4, st5, st6, st7;
  s16x8 st8, st9, st10, st11, st12, st13, st14, st15;
  float rs = 0.f;

#define WINDOW_A(W, ST)                                              \
  do {                                                               \
    const unsigned char* kb8 = Stg + ((W) & 3) * 8192;               \
    s16x8 ka0 = *(const s16x8*)(kb8 + lb);                           \
    s16x8 ka1 = *(const s16x8*)(kb8 + 1024 + lb);                    \
    s16x8 ka2 = *(const s16x8*)(kb8 + 2048 + lb);                    \
    s16x8 ka3 = *(const s16x8*)(kb8 + 3072 + lb);                    \
    s16x8 kb0 = *(const s16x8*)(kb8 + 4096 + lb);                    \
    s16x8 kb1 = *(const s16x8*)(kb8 + 5120 + lb);                    \
    s16x8 kb2 = *(const s16x8*)(kb8 + 6144 + lb);                    \
    s16x8 kb3 = *(const s16x8*)(kb8 + 7168 + lb);                    \
    f32x4 sA = {0.f, 0.f, 0.f, 0.f}, sB = {0.f, 0.f, 0.f, 0.f};      \
    sA = MFMA16(ka0, qf0, sA); sA = MFMA16(ka1, qf1, sA);            \
    sA = MFMA16(ka2, qf2, sA); sA = MFMA16(ka3, qf3, sA);            \
    sB = MFMA16(kb0, qf0, sB); sB = MFMA16(kb1, qf1, sB);            \
    sB = MFMA16(kb2, qf2, sB); sB = MFMA16(kb3, qf3, sB);            \
    s16x8 fr;                                                        \
    float e;                                                         \
    e = __expf(sA[0] * scale); rs += e; fr[0] = (short)f2bf(e);      \
    e = __expf(sA[1] * scale); rs += e; fr[1] = (short)f2bf(e);      \
    e = __expf(sA[2] * scale); rs += e; fr[2] = (short)f2bf(e);      \
    e = __expf(sA[3] * scale); rs += e; fr[3] = (short)f2bf(e);      \
    e = __expf(sB[0] * scale); rs += e; fr[4] = (short)f2bf(e);      \
    e = __expf(sB[1] * scale); rs += e; fr[5] = (short)f2bf(e);      \
    e = __expf(sB[2] * scale); rs += e; fr[6] = (short)f2bf(e);      \
    e = __expf(sB[3] * scale); rs += e; fr[7] = (short)f2bf(e);      \
    ST = fr;                                                         \
  } while (0)

#define STEPA(W, ST)                                                 \
  do { vmwait<2>(); blockbar(); stageK((W) + 3); WINDOW_A(W, ST); } while (0)

  // ---- phase A: 3-deep prefetched K windows (1 load/wave/window) ----
  stageK(0); stageK(1); stageK(2);
  STEPA(0, st0);  STEPA(1, st1);  STEPA(2, st2);  STEPA(3, st3);
  STEPA(4, st4);  STEPA(5, st5);  STEPA(6, st6);  STEPA(7, st7);
  STEPA(8, st8);  STEPA(9, st9);  STEPA(10, st10); STEPA(11, st11);
  STEPA(12, st12);
  vmwait<2>(); blockbar(); WINDOW_A(13, st13);
  vmwait<1>(); blockbar(); WINDOW_A(14, st14);
  vmwait<0>(); blockbar(); WINDOW_A(15, st15);

  // full rowsum for row l15 (combine the 4 g-partials)
  rs += __shfl_xor(rs, 16);
  rs += __shfl_xor(rs, 32);
  const float inv = 1.0f / rs;

  blockbar();  // all waves done with K reads before V staging reuses Stg

  // ---- phase B: 3-deep prefetched V windows, PV from named stash ----
  f32x4 acc2[8];
#pragma unroll
  for (int f = 0; f < 8; ++f) acc2[f] = (f32x4){0.f, 0.f, 0.f, 0.f};

#define WINDOW_B(W, ST)                                                    \
  do {                                                                     \
    const s16x8 pc = ST;                                                   \
    const unsigned char* vb8 = Stg + ((W) & 3) * 8192;                     \
    acc2[0] = MFMA16(pc, *(const s16x8*)(vb8 + lb), acc2[0]);              \
    acc2[1] = MFMA16(pc, *(const s16x8*)(vb8 + 1024 + lb), acc2[1]);       \
    acc2[2] = MFMA16(pc, *(const s16x8*)(vb8 + 2048 + lb), acc2[2]);       \
    acc2[3] = MFMA16(pc, *(const s16x8*)(vb8 + 3072 + lb), acc2[3]);       \
    acc2[4] = MFMA16(pc, *(const s16x8*)(vb8 + 4096 + lb), acc2[4]);       \
    acc2[5] = MFMA16(pc, *(const s16x8*)(vb8 + 5120 + lb), acc2[5]);       \
    acc2[6] = MFMA16(pc, *(const s16x8*)(vb8 + 6144 + lb), acc2[6]);       \
    acc2[7] = MFMA16(pc, *(const s16x8*)(vb8 + 7168 + lb), acc2[7]);       \
  } while (0)

#define STEPB(W, ST)                                                 \
  do { vmwait<2>(); blockbar(); stageV((W) + 3); WINDOW_B(W, ST); } while (0)

  stageV(0); stageV(1); stageV(2);
  STEPB(0, st0);  STEPB(1, st1);  STEPB(2, st2);  STEPB(3, st3);
  STEPB(4, st4);  STEPB(5, st5);  STEPB(6, st6);  STEPB(7, st7);
  STEPB(8, st8);  STEPB(9, st9);  STEPB(10, st10); STEPB(11, st11);
  STEPB(12, st12);
  vmwait<2>(); blockbar(); WINDOW_B(13, st13);
  vmwait<1>(); blockbar(); WINDOW_B(14, st14);
  vmwait<0>(); blockbar(); WINDOW_B(15, st15);

  // ---- phase C: attn from named stash (fire-and-forget stores) ----
  float* ap = attn_out + (size_t)head * 262144 + (size_t)(h0 + 16 * wave + l15) * 512 + 8 * g;

#define OUTW(W, ST)                                                  \
  do {                                                               \
    const s16x8 pc = ST;                                             \
    f32x4 o0, o1;                                                    \
    o0[0] = bf2f((unsigned short)pc[0]) * inv;                       \
    o0[1] = bf2f((unsigned short)pc[1]) * inv;                       \
    o0[2] = bf2f((unsigned short)pc[2]) * inv;                       \
    o0[3] = bf2f((unsigned short)pc[3]) * inv;                       \
    o1[0] = bf2f((unsigned short)pc[4]) * inv;                       \
    o1[1] = bf2f((unsigned short)pc[5]) * inv;                       \
    o1[2] = bf2f((unsigned short)pc[6]) * inv;                       \
    o1[3] = bf2f((unsigned short)pc[7]) * inv;                       \
    *(f32x4*)(ap + (W) * 32) = o0;                                   \
    *(f32x4*)(ap + (W) * 32 + 4) = o1;                               \
  } while (0)

  OUTW(0, st0);  OUTW(1, st1);  OUTW(2, st2);  OUTW(3, st3);
  OUTW(4, st4);  OUTW(5, st5);  OUTW(6, st6);  OUTW(7, st7);
  OUTW(8, st8);  OUTW(9, st9);  OUTW(10, st10); OUTW(11, st11);
  OUTW(12, st12); OUTW(13, st13); OUTW(14, st14); OUTW(15, st15);

  // ---- out0 (normalized, NT: 64B-sector-aligned pattern) ----
  float invm[4];
#pragma unroll
  for (int r = 0; r < 4; ++r) invm[r] = __shfl(inv, 4 * g + r);

  float* op = out0 + khead + (size_t)(h0 + 16 * wave + 4 * g) * 128 + l15;
#pragma unroll
  for (int f = 0; f < 8; ++f)
#pragma unroll
    for (int r = 0; r < 4; ++r)
      __builtin_nontemporal_store(acc2[f][r] * invm[r], op + (size_t)r * 128 + f * 16);
}

extern "C" void kernel_launch(void* const* d_in, const int* in_sizes, int n_in,
                              void* d_out, int out_size, void* d_ws, size_t ws_size,
                              hipStream_t stream) {
  const float* q  = (const float*)d_in[0];
  const float* k  = (const float*)d_in[1];
  const float* v  = (const float*)d_in[2];
  const float* Wq = (const float*)d_in[3];
  const float* bq = (const float*)d_in[4];
  const float* Wk = (const float*)d_in[5];
  const float* bk = (const float*)d_in[6];
  const float* Wv = (const float*)d_in[7];
  const float* bv = (const float*)d_in[8];

  unsigned short* Qt = (unsigned short*)d_ws;       // (unused; layout kept)
  unsigned short* Kt = Qt + 33554432;               // 64 MiB
  unsigned short* Vf = Kt + 33554432;               // 64 MiB
  float* out0 = (float*)d_out;                      // 33,554,432 fp32
  float* attn = out0 + 33554432;                    // 134,217,728 fp32

  dim3 pgrid(512, 2, 1);
  proj_kernel<<<pgrid, 256, 0, stream>>>(k, v, Wk, bk, Wv, bv, Kt, Vf);
  fattn_kernel<<<2048, 512, 0, stream>>>(q, Wq, bq, Kt, Vf, out0, attn);
}